// Round 1
// baseline (382.517 us; speedup 1.0000x reference)
//
#include <hip/hip_runtime.h>
#include <math.h>

typedef __bf16 bf16_t;
typedef bf16_t bf16x8 __attribute__((ext_vector_type(8)));
typedef bf16_t bf16x4 __attribute__((ext_vector_type(4)));
typedef float  f32x4  __attribute__((ext_vector_type(4)));
typedef float  floatv4 __attribute__((ext_vector_type(4)));

#define AS1 __attribute__((address_space(1)))
#define AS3 __attribute__((address_space(3)))

static __device__ __forceinline__ void gld_lds16(const void* g, void* l) {
  __builtin_amdgcn_global_load_lds((const AS1 unsigned int*)g,
                                   (AS3 unsigned int*)l, 16, 0, 0);
}

// ---------------- cast f32 -> bf16, 4 elems/thread ----------------
__global__ __launch_bounds__(256) void k_cast(const float* __restrict__ in,
                                              bf16_t* __restrict__ out, int n4) {
  int i = blockIdx.x * 256 + threadIdx.x;
  if (i >= n4) return;
  floatv4 v = ((const floatv4*)in)[i];
  bf16x4 o;
  o.x = (bf16_t)v.x; o.y = (bf16_t)v.y; o.z = (bf16_t)v.z; o.w = (bf16_t)v.w;
  ((bf16x4*)out)[i] = o;
}

// ---------------- transpose + cast: in f32 [R][Cc] -> out bf16 [Cc][R] ----------------
__global__ __launch_bounds__(256) void k_transpose_cast(const float* __restrict__ in,
                                                        bf16_t* __restrict__ out,
                                                        int R, int Cc) {
  __shared__ float tile[32][33];
  int c0 = blockIdx.x * 32, r0 = blockIdx.y * 32;
  int tx = threadIdx.x, ty = threadIdx.y;  // 32 x 8
#pragma unroll
  for (int i = 0; i < 32; i += 8)
    tile[ty + i][tx] = in[(size_t)(r0 + ty + i) * Cc + c0 + tx];
  __syncthreads();
#pragma unroll
  for (int i = 0; i < 32; i += 8)
    out[(size_t)(c0 + ty + i) * R + r0 + tx] = (bf16_t)tile[tx][ty + i];
}

// ---------------- GEMM1: qkv = X @ Wt^T, scatter to q/k/v(trans) bf16 ----------------
__global__ __launch_bounds__(256) void k_gemm_qkv(
    const bf16_t* __restrict__ A, const bf16_t* __restrict__ Bt,
    const float* __restrict__ bias,
    bf16_t* __restrict__ qo, bf16_t* __restrict__ ko, bf16_t* __restrict__ vto) {
  const int K = 1024;
  __shared__ bf16_t As[128 * 32];
  __shared__ bf16_t Bs[128 * 32];
  const int m0 = blockIdx.x * 128, n0 = blockIdx.y * 128;
  const int t = threadIdx.x, lane = t & 63, w = t >> 6;
  const int wr = w >> 1, wc = w & 1;
  const int ln15 = lane & 15, lhi = lane >> 4;

  f32x4 acc[4][4];
#pragma unroll
  for (int m = 0; m < 4; ++m)
#pragma unroll
    for (int n = 0; n < 4; ++n) acc[m][n] = (f32x4){0.f, 0.f, 0.f, 0.f};

  const int sr = t >> 2, sc = (t & 3) * 8;
  const bf16_t* Ab = A + (size_t)(m0 + sr) * K + sc;
  const bf16_t* Bb = Bt + (size_t)(n0 + sr) * K + sc;
  char* AsDst = (char*)As + t * 16;
  char* BsDst = (char*)Bs + t * 16;

  for (int k0 = 0; k0 < K; k0 += 32) {
    gld_lds16(Ab + k0, AsDst);
    gld_lds16(Ab + 64 * K + k0, AsDst + 4096);
    gld_lds16(Bb + k0, BsDst);
    gld_lds16(Bb + 64 * K + k0, BsDst + 4096);
    __syncthreads();
    bf16x8 af[4], bfr[4];
#pragma unroll
    for (int m = 0; m < 4; ++m)
      af[m] = *(const bf16x8*)&As[(wr * 64 + m * 16 + ln15) * 32 + lhi * 8];
#pragma unroll
    for (int n = 0; n < 4; ++n)
      bfr[n] = *(const bf16x8*)&Bs[(wc * 64 + n * 16 + ln15) * 32 + lhi * 8];
#pragma unroll
    for (int m = 0; m < 4; ++m)
#pragma unroll
      for (int n = 0; n < 4; ++n)
        acc[m][n] = __builtin_amdgcn_mfma_f32_16x16x32_bf16(af[m], bfr[n], acc[m][n], 0, 0, 0);
    __syncthreads();
  }
#pragma unroll
  for (int n = 0; n < 4; ++n) {
    int col = n0 + wc * 64 + n * 16 + ln15;
    float bv = bias[col];
    int which = col >> 10;
    int cc = col & 1023;
    int h = cc >> 6, d = cc & 63;
#pragma unroll
    for (int m = 0; m < 4; ++m)
#pragma unroll
      for (int j = 0; j < 4; ++j) {
        int row = m0 + wr * 64 + m * 16 + lhi * 4 + j;
        int b = row >> 11, tt = row & 2047;
        bf16_t o = (bf16_t)(acc[m][n][j] + bv);
        size_t bh = (size_t)(b * 16 + h);
        if (which == 0)      qo[(bh * 2048 + tt) * 64 + d] = o;
        else if (which == 1) ko[(bh * 2048 + tt) * 64 + d] = o;
        else                 vto[(bh * 64 + d) * 2048 + tt] = o;
      }
  }
}

// ---------------- flash attention, causal/anti-causal ----------------
__global__ __launch_bounds__(256) void k_attn(
    const bf16_t* __restrict__ q, const bf16_t* __restrict__ k,
    const bf16_t* __restrict__ vt, const int* __restrict__ dirp,
    bf16_t* __restrict__ a2) {
  const int T = 2048;
  __shared__ bf16_t P[4][16][32];
  const int bh = blockIdx.x, b = bh >> 4, h = bh & 15;
  const int qt = blockIdx.y;
  const int t = threadIdx.x, lane = t & 63, w = t >> 6;
  const int ln15 = lane & 15, lhi = lane >> 4;
  const int q0 = qt * 64 + w * 16;
  const bool anti = (*dirp == 1);
  const float scale = 0.125f;

  const bf16_t* qb = q + ((size_t)bh * T + q0 + ln15) * 64 + lhi * 8;
  bf16x8 qf0 = *(const bf16x8*)qb;
  bf16x8 qf1 = *(const bf16x8*)(qb + 32);

  f32x4 oacc[4];
#pragma unroll
  for (int df = 0; df < 4; ++df) oacc[df] = (f32x4){0.f, 0.f, 0.f, 0.f};
  float mrun[4], lrun[4];
#pragma unroll
  for (int j = 0; j < 4; ++j) { mrun[j] = -3.0e38f; lrun[j] = 0.f; }

  const bf16_t* kbase = k + (size_t)bh * T * 64;
  const bf16_t* vbase = vt + (size_t)bh * 64 * T;

  int kt0, kt1;
  if (anti) { kt0 = q0 >> 5; kt1 = T >> 5; }
  else      { kt0 = 0;       kt1 = ((q0 + 15) >> 5) + 1; }

  for (int kt = kt0; kt < kt1; ++kt) {
    const int kc0 = kt * 32;
    f32x4 s[2];
#pragma unroll
    for (int n = 0; n < 2; ++n) {
      const bf16_t* kr = kbase + (size_t)(kc0 + n * 16 + ln15) * 64 + lhi * 8;
      bf16x8 b0 = *(const bf16x8*)kr;
      bf16x8 b1 = *(const bf16x8*)(kr + 32);
      f32x4 z = (f32x4){0.f, 0.f, 0.f, 0.f};
      z = __builtin_amdgcn_mfma_f32_16x16x32_bf16(qf0, b0, z, 0, 0, 0);
      z = __builtin_amdgcn_mfma_f32_16x16x32_bf16(qf1, b1, z, 0, 0, 0);
      s[n] = z;
    }
#pragma unroll
    for (int j = 0; j < 4; ++j) {
      const int row = q0 + lhi * 4 + j;
      float s0 = s[0][j] * scale;
      float s1 = s[1][j] * scale;
      const int c0i = kc0 + ln15, c1i = kc0 + 16 + ln15;
      bool ok0 = anti ? (c0i >= row) : (c0i <= row);
      bool ok1 = anti ? (c1i >= row) : (c1i <= row);
      s0 = ok0 ? s0 : -3.0e38f;
      s1 = ok1 ? s1 : -3.0e38f;
      float vm = fmaxf(s0, s1);
#pragma unroll
      for (int off = 1; off < 16; off <<= 1) vm = fmaxf(vm, __shfl_xor(vm, off));
      const float mn = fmaxf(mrun[j], vm);
      const float al = __expf(mrun[j] - mn);
      const float p0 = ok0 ? __expf(s0 - mn) : 0.f;
      const float p1 = ok1 ? __expf(s1 - mn) : 0.f;
      float rs = p0 + p1;
#pragma unroll
      for (int off = 1; off < 16; off <<= 1) rs += __shfl_xor(rs, off);
      lrun[j] = lrun[j] * al + rs;
      mrun[j] = mn;
#pragma unroll
      for (int df = 0; df < 4; ++df) oacc[df][j] *= al;
      P[w][lhi * 4 + j][ln15]      = (bf16_t)p0;
      P[w][lhi * 4 + j][16 + ln15] = (bf16_t)p1;
    }
    __asm__ volatile("s_waitcnt lgkmcnt(0)" ::: "memory");
    bf16x8 pa = *(const bf16x8*)&P[w][ln15][lhi * 8];
#pragma unroll
    for (int df = 0; df < 4; ++df) {
      const bf16_t* vr = vbase + (size_t)(df * 16 + ln15) * T + kc0 + lhi * 8;
      bf16x8 bv = *(const bf16x8*)vr;
      oacc[df] = __builtin_amdgcn_mfma_f32_16x16x32_bf16(pa, bv, oacc[df], 0, 0, 0);
    }
  }
#pragma unroll
  for (int df = 0; df < 4; ++df)
#pragma unroll
    for (int j = 0; j < 4; ++j) {
      const int row = q0 + lhi * 4 + j;
      float o = oacc[df][j] / lrun[j];
      a2[((size_t)b * T + row) * 1024 + h * 64 + df * 16 + ln15] = (bf16_t)o;
    }
}

// ---------------- GEMM2: out = A2 @ Wp^T + bias, fp32 out ----------------
__global__ __launch_bounds__(256) void k_gemm_proj(
    const bf16_t* __restrict__ A, const bf16_t* __restrict__ Bt,
    const float* __restrict__ bias, float* __restrict__ out) {
  const int K = 1024;
  __shared__ bf16_t As[128 * 32];
  __shared__ bf16_t Bs[128 * 32];
  const int m0 = blockIdx.x * 128, n0 = blockIdx.y * 128;
  const int t = threadIdx.x, lane = t & 63, w = t >> 6;
  const int wr = w >> 1, wc = w & 1;
  const int ln15 = lane & 15, lhi = lane >> 4;

  f32x4 acc[4][4];
#pragma unroll
  for (int m = 0; m < 4; ++m)
#pragma unroll
    for (int n = 0; n < 4; ++n) acc[m][n] = (f32x4){0.f, 0.f, 0.f, 0.f};

  const int sr = t >> 2, sc = (t & 3) * 8;
  const bf16_t* Ab = A + (size_t)(m0 + sr) * K + sc;
  const bf16_t* Bb = Bt + (size_t)(n0 + sr) * K + sc;
  char* AsDst = (char*)As + t * 16;
  char* BsDst = (char*)Bs + t * 16;

  for (int k0 = 0; k0 < K; k0 += 32) {
    gld_lds16(Ab + k0, AsDst);
    gld_lds16(Ab + 64 * K + k0, AsDst + 4096);
    gld_lds16(Bb + k0, BsDst);
    gld_lds16(Bb + 64 * K + k0, BsDst + 4096);
    __syncthreads();
    bf16x8 af[4], bfr[4];
#pragma unroll
    for (int m = 0; m < 4; ++m)
      af[m] = *(const bf16x8*)&As[(wr * 64 + m * 16 + ln15) * 32 + lhi * 8];
#pragma unroll
    for (int n = 0; n < 4; ++n)
      bfr[n] = *(const bf16x8*)&Bs[(wc * 64 + n * 16 + ln15) * 32 + lhi * 8];
#pragma unroll
    for (int m = 0; m < 4; ++m)
#pragma unroll
      for (int n = 0; n < 4; ++n)
        acc[m][n] = __builtin_amdgcn_mfma_f32_16x16x32_bf16(af[m], bfr[n], acc[m][n], 0, 0, 0);
    __syncthreads();
  }
#pragma unroll
  for (int n = 0; n < 4; ++n) {
    int col = n0 + wc * 64 + n * 16 + ln15;
    float bv = bias[col];
#pragma unroll
    for (int m = 0; m < 4; ++m)
#pragma unroll
      for (int j = 0; j < 4; ++j) {
        int row = m0 + wr * 64 + m * 16 + lhi * 4 + j;
        out[(size_t)row * 1024 + col] = acc[m][n][j] + bv;
      }
  }
}

extern "C" void kernel_launch(void* const* d_in, const int* in_sizes, int n_in,
                              void* d_out, int out_size, void* d_ws, size_t ws_size,
                              hipStream_t stream) {
  (void)in_sizes; (void)n_in; (void)out_size; (void)ws_size;
  const float* x      = (const float*)d_in[0];
  const int*   dirp   = (const int*)d_in[1];
  const float* qkv_w  = (const float*)d_in[2];
  const float* qkv_b  = (const float*)d_in[3];
  const float* proj_w = (const float*)d_in[4];
  const float* proj_b = (const float*)d_in[5];
  float* out = (float*)d_out;

  char* ws = (char*)d_ws;
  bf16_t* xb   = (bf16_t*)(ws);                       // 16,777,216 B (reused as a2 after GEMM1)
  bf16_t* wq_t = (bf16_t*)(ws + 16777216);            //  6,291,456 B
  bf16_t* wp_t = (bf16_t*)(ws + 23068672);            //  2,097,152 B
  bf16_t* qb   = (bf16_t*)(ws + 25165824);            // 16,777,216 B
  bf16_t* kb   = (bf16_t*)(ws + 41943040);            // 16,777,216 B
  bf16_t* vtb  = (bf16_t*)(ws + 58720256);            // 16,777,216 B  (end: 75,497,472)
  bf16_t* a2   = xb;

  k_cast<<<8192, 256, 0, stream>>>(x, xb, 2097152);
  k_transpose_cast<<<dim3(96, 32), dim3(32, 8), 0, stream>>>(qkv_w, wq_t, 1024, 3072);
  k_transpose_cast<<<dim3(32, 32), dim3(32, 8), 0, stream>>>(proj_w, wp_t, 1024, 1024);
  k_gemm_qkv<<<dim3(64, 24), 256, 0, stream>>>(xb, wq_t, qkv_b, qb, kb, vtb);
  k_attn<<<dim3(64, 32), 256, 0, stream>>>(qb, kb, vtb, dirp, a2);
  k_gemm_proj<<<dim3(64, 8), 256, 0, stream>>>(a2, wp_t, proj_b, out);
}

// Round 2
// 355.995 us; speedup vs baseline: 1.0745x; 1.0745x over previous
//
#include <hip/hip_runtime.h>
#include <math.h>

typedef __bf16 bf16_t;
typedef bf16_t bf16x8 __attribute__((ext_vector_type(8)));
typedef bf16_t bf16x4 __attribute__((ext_vector_type(4)));
typedef float  f32x4  __attribute__((ext_vector_type(4)));
typedef float  floatv4 __attribute__((ext_vector_type(4)));

#define AS1 __attribute__((address_space(1)))
#define AS3 __attribute__((address_space(3)))

static __device__ __forceinline__ void gld_lds16(const void* g, void* l) {
  __builtin_amdgcn_global_load_lds((const AS1 unsigned int*)g,
                                   (AS3 unsigned int*)l, 16, 0, 0);
}

// ---------------- cast f32 -> bf16, 4 elems/thread ----------------
__global__ __launch_bounds__(256) void k_cast(const float* __restrict__ in,
                                              bf16_t* __restrict__ out, int n4) {
  int i = blockIdx.x * 256 + threadIdx.x;
  if (i >= n4) return;
  floatv4 v = ((const floatv4*)in)[i];
  bf16x4 o;
  o.x = (bf16_t)v.x; o.y = (bf16_t)v.y; o.z = (bf16_t)v.z; o.w = (bf16_t)v.w;
  ((bf16x4*)out)[i] = o;
}

// ---------------- transpose + cast: in f32 [R][Cc] -> out bf16 [Cc][R] ----------------
__global__ __launch_bounds__(256) void k_transpose_cast(const float* __restrict__ in,
                                                        bf16_t* __restrict__ out,
                                                        int R, int Cc) {
  __shared__ float tile[32][33];
  int c0 = blockIdx.x * 32, r0 = blockIdx.y * 32;
  int tx = threadIdx.x, ty = threadIdx.y;  // 32 x 8
#pragma unroll
  for (int i = 0; i < 32; i += 8)
    tile[ty + i][tx] = in[(size_t)(r0 + ty + i) * Cc + c0 + tx];
  __syncthreads();
#pragma unroll
  for (int i = 0; i < 32; i += 8)
    out[(size_t)(c0 + ty + i) * R + r0 + tx] = (bf16_t)tile[tx][ty + i];
}

// ---------------- GEMM1: qkv = X @ Wt^T, scatter to q/k/v(trans) bf16 ----------------
__global__ __launch_bounds__(256) void k_gemm_qkv(
    const bf16_t* __restrict__ A, const bf16_t* __restrict__ Bt,
    const float* __restrict__ bias,
    bf16_t* __restrict__ qo, bf16_t* __restrict__ ko, bf16_t* __restrict__ vto) {
  const int K = 1024;
  __shared__ bf16_t As[128 * 32];
  __shared__ bf16_t Bs[128 * 32];
  const int m0 = blockIdx.x * 128, n0 = blockIdx.y * 128;
  const int t = threadIdx.x, lane = t & 63, w = t >> 6;
  const int wr = w >> 1, wc = w & 1;
  const int ln15 = lane & 15, lhi = lane >> 4;

  f32x4 acc[4][4];
#pragma unroll
  for (int m = 0; m < 4; ++m)
#pragma unroll
    for (int n = 0; n < 4; ++n) acc[m][n] = (f32x4){0.f, 0.f, 0.f, 0.f};

  const int sr = t >> 2, sc = (t & 3) * 8;
  const bf16_t* Ab = A + (size_t)(m0 + sr) * K + sc;
  const bf16_t* Bb = Bt + (size_t)(n0 + sr) * K + sc;
  char* AsDst = (char*)As + t * 16;
  char* BsDst = (char*)Bs + t * 16;

  for (int k0 = 0; k0 < K; k0 += 32) {
    gld_lds16(Ab + k0, AsDst);
    gld_lds16(Ab + 64 * K + k0, AsDst + 4096);
    gld_lds16(Bb + k0, BsDst);
    gld_lds16(Bb + 64 * K + k0, BsDst + 4096);
    __syncthreads();
    bf16x8 af[4], bfr[4];
#pragma unroll
    for (int m = 0; m < 4; ++m)
      af[m] = *(const bf16x8*)&As[(wr * 64 + m * 16 + ln15) * 32 + lhi * 8];
#pragma unroll
    for (int n = 0; n < 4; ++n)
      bfr[n] = *(const bf16x8*)&Bs[(wc * 64 + n * 16 + ln15) * 32 + lhi * 8];
#pragma unroll
    for (int m = 0; m < 4; ++m)
#pragma unroll
      for (int n = 0; n < 4; ++n)
        acc[m][n] = __builtin_amdgcn_mfma_f32_16x16x32_bf16(af[m], bfr[n], acc[m][n], 0, 0, 0);
    __syncthreads();
  }
#pragma unroll
  for (int n = 0; n < 4; ++n) {
    int col = n0 + wc * 64 + n * 16 + ln15;
    float bv = bias[col];
    int which = col >> 10;
    int cc = col & 1023;
    int h = cc >> 6, d = cc & 63;
#pragma unroll
    for (int m = 0; m < 4; ++m)
#pragma unroll
      for (int j = 0; j < 4; ++j) {
        int row = m0 + wr * 64 + m * 16 + lhi * 4 + j;
        int b = row >> 11, tt = row & 2047;
        bf16_t o = (bf16_t)(acc[m][n][j] + bv);
        size_t bh = (size_t)(b * 16 + h);
        if (which == 0)      qo[(bh * 2048 + tt) * 64 + d] = o;
        else if (which == 1) ko[(bh * 2048 + tt) * 64 + d] = o;
        else                 vto[(bh * 64 + d) * 2048 + tt] = o;
      }
  }
}

// ---------------- flash attention v2: swapped QK^T, register softmax ----------------
// Per wave: 16 q-rows. S^T = mfma(Kfrag, Qfrag) with permuted K-row order so each
// lane (q=ln15, lhi) holds S for k = kc0 + lhi*8 + 0..7 -> directly the PV B-fragment.
__device__ __forceinline__ void ldK(const bf16_t* kl, int kc0, bf16x8 kf[4]) {
#pragma unroll
  for (int c = 0; c < 2; ++c)
#pragma unroll
    for (int h2 = 0; h2 < 2; ++h2)
      kf[c * 2 + h2] = *(const bf16x8*)(kl + (size_t)(kc0 + c * 4) * 64 + h2 * 32);
}
__device__ __forceinline__ void ldV(const bf16_t* vl, int kc0, bf16x8 vf[4]) {
#pragma unroll
  for (int g = 0; g < 4; ++g)
    vf[g] = *(const bf16x8*)(vl + (size_t)g * 16 * 2048 + kc0);
}

__device__ __forceinline__ void ptile(
    int kc0, int qrow, int q0, bool anti, int lhi,
    const bf16x8 qf0, const bf16x8 qf1,
    const bf16x8 kf[4], const bf16x8 vf[4],
    f32x4 acc[4], float& mrun, float& lrun) {
  const float C = 0.18033688011112042f;  // 0.125 * log2(e)
  const f32x4 z = (f32x4){0.f, 0.f, 0.f, 0.f};
  f32x4 s0 = __builtin_amdgcn_mfma_f32_16x16x32_bf16(kf[0], qf0, z, 0, 0, 0);
  s0 = __builtin_amdgcn_mfma_f32_16x16x32_bf16(kf[1], qf1, s0, 0, 0, 0);
  f32x4 s1 = __builtin_amdgcn_mfma_f32_16x16x32_bf16(kf[2], qf0, z, 0, 0, 0);
  s1 = __builtin_amdgcn_mfma_f32_16x16x32_bf16(kf[3], qf1, s1, 0, 0, 0);

  float sc[8];
#pragma unroll
  for (int j = 0; j < 4; ++j) { sc[j] = s0[j] * C; sc[4 + j] = s1[j] * C; }

  const bool needm = anti ? (kc0 < q0 + 15) : (kc0 + 31 > q0);
  if (needm) {
#pragma unroll
    for (int e = 0; e < 8; ++e) {
      int col = kc0 + lhi * 8 + e;
      bool ok = anti ? (col >= qrow) : (col <= qrow);
      sc[e] = ok ? sc[e] : -3.0e38f;
    }
  }
  float vm = sc[0];
#pragma unroll
  for (int e = 1; e < 8; ++e) vm = fmaxf(vm, sc[e]);
  vm = fmaxf(vm, __shfl_xor(vm, 16));
  vm = fmaxf(vm, __shfl_xor(vm, 32));
  if (!__all(vm <= mrun)) {
    float mn = fmaxf(mrun, vm);
    float al = __builtin_exp2f(mrun - mn);
    lrun *= al;
#pragma unroll
    for (int g = 0; g < 4; ++g) acc[g] *= al;
    mrun = mn;
  }
  float p[8];
  float rs = 0.f;
#pragma unroll
  for (int e = 0; e < 8; ++e) { p[e] = __builtin_exp2f(sc[e] - mrun); rs += p[e]; }
  rs += __shfl_xor(rs, 16);
  rs += __shfl_xor(rs, 32);
  lrun += rs;
  bf16x8 pb;
#pragma unroll
  for (int e = 0; e < 8; ++e) pb[e] = (bf16_t)p[e];
#pragma unroll
  for (int g = 0; g < 4; ++g)
    acc[g] = __builtin_amdgcn_mfma_f32_16x16x32_bf16(vf[g], pb, acc[g], 0, 0, 0);
}

__global__ __launch_bounds__(256) void k_attn2(
    const bf16_t* __restrict__ q, const bf16_t* __restrict__ k,
    const bf16_t* __restrict__ vt, const int* __restrict__ dirp,
    bf16_t* __restrict__ a2) {
  const int T = 2048;
  const int bh = blockIdx.x, b = bh >> 4, h = bh & 15;
  const int jb = blockIdx.y;  // pair index: q-tiles {jb, 31-jb} -> uniform work
  const int t = threadIdx.x, lane = t & 63, w = t >> 6;
  const int ln15 = lane & 15, lhi = lane >> 4;
  const bool anti = (*dirp == 1);

  const bf16_t* kbase = k + (size_t)bh * T * 64;
  const bf16_t* vbase = vt + (size_t)bh * 64 * T;
  const int krow_off = (ln15 >> 2) * 8 + (ln15 & 3);  // permuted K-row order
  const bf16_t* kl = kbase + (size_t)krow_off * 64 + lhi * 8;
  const bf16_t* vl = vbase + (size_t)ln15 * T + lhi * 8;

#pragma unroll 1
  for (int sel = 0; sel < 2; ++sel) {
    const int qt = sel ? (31 - jb) : jb;
    const int q0 = qt * 64 + w * 16;
    const int qrow = q0 + ln15;

    const bf16_t* qp = q + ((size_t)bh * T + qrow) * 64 + lhi * 8;
    bf16x8 qf0 = *(const bf16x8*)qp;
    bf16x8 qf1 = *(const bf16x8*)(qp + 32);

    f32x4 acc[4];
#pragma unroll
    for (int g = 0; g < 4; ++g) acc[g] = (f32x4){0.f, 0.f, 0.f, 0.f};
    float mrun = -3.0e38f, lrun = 0.f;

    int kt0, kt1;
    if (anti) { kt0 = q0 >> 5; kt1 = 64; }
    else      { kt0 = 0;       kt1 = ((q0 + 15) >> 5) + 1; }

    bf16x8 kfa[4], kfb[4], vf[4];
    ldK(kl, kt0 * 32, kfa);
    int kt = kt0;
    while (true) {
      int kc0 = kt * 32;
      ldV(vl, kc0, vf);
      if (kt + 1 < kt1) ldK(kl, (kt + 1) * 32, kfb);
      ptile(kc0, qrow, q0, anti, lhi, qf0, qf1, kfa, vf, acc, mrun, lrun);
      ++kt; if (kt >= kt1) break;
      kc0 = kt * 32;
      ldV(vl, kc0, vf);
      if (kt + 1 < kt1) ldK(kl, (kt + 1) * 32, kfa);
      ptile(kc0, qrow, q0, anti, lhi, qf0, qf1, kfb, vf, acc, mrun, lrun);
      ++kt; if (kt >= kt1) break;
    }

    float inv = __builtin_amdgcn_rcpf(lrun);
    bf16_t* op = a2 + ((size_t)b * T + qrow) * 1024 + h * 64 + lhi * 4;
#pragma unroll
    for (int g = 0; g < 4; ++g) {
      bf16x4 o4;
#pragma unroll
      for (int jx = 0; jx < 4; ++jx) o4[jx] = (bf16_t)(acc[g][jx] * inv);
      *(bf16x4*)(op + g * 16) = o4;
    }
  }
}

// ---------------- GEMM2: out = A2 @ Wp^T + bias, fp32 out ----------------
__global__ __launch_bounds__(256) void k_gemm_proj(
    const bf16_t* __restrict__ A, const bf16_t* __restrict__ Bt,
    const float* __restrict__ bias, float* __restrict__ out) {
  const int K = 1024;
  __shared__ bf16_t As[128 * 32];
  __shared__ bf16_t Bs[128 * 32];
  const int m0 = blockIdx.x * 128, n0 = blockIdx.y * 128;
  const int t = threadIdx.x, lane = t & 63, w = t >> 6;
  const int wr = w >> 1, wc = w & 1;
  const int ln15 = lane & 15, lhi = lane >> 4;

  f32x4 acc[4][4];
#pragma unroll
  for (int m = 0; m < 4; ++m)
#pragma unroll
    for (int n = 0; n < 4; ++n) acc[m][n] = (f32x4){0.f, 0.f, 0.f, 0.f};

  const int sr = t >> 2, sc = (t & 3) * 8;
  const bf16_t* Ab = A + (size_t)(m0 + sr) * K + sc;
  const bf16_t* Bb = Bt + (size_t)(n0 + sr) * K + sc;
  char* AsDst = (char*)As + t * 16;
  char* BsDst = (char*)Bs + t * 16;

  for (int k0 = 0; k0 < K; k0 += 32) {
    gld_lds16(Ab + k0, AsDst);
    gld_lds16(Ab + 64 * K + k0, AsDst + 4096);
    gld_lds16(Bb + k0, BsDst);
    gld_lds16(Bb + 64 * K + k0, BsDst + 4096);
    __syncthreads();
    bf16x8 af[4], bfr[4];
#pragma unroll
    for (int m = 0; m < 4; ++m)
      af[m] = *(const bf16x8*)&As[(wr * 64 + m * 16 + ln15) * 32 + lhi * 8];
#pragma unroll
    for (int n = 0; n < 4; ++n)
      bfr[n] = *(const bf16x8*)&Bs[(wc * 64 + n * 16 + ln15) * 32 + lhi * 8];
#pragma unroll
    for (int m = 0; m < 4; ++m)
#pragma unroll
      for (int n = 0; n < 4; ++n)
        acc[m][n] = __builtin_amdgcn_mfma_f32_16x16x32_bf16(af[m], bfr[n], acc[m][n], 0, 0, 0);
    __syncthreads();
  }
#pragma unroll
  for (int n = 0; n < 4; ++n) {
    int col = n0 + wc * 64 + n * 16 + ln15;
    float bv = bias[col];
#pragma unroll
    for (int m = 0; m < 4; ++m)
#pragma unroll
      for (int j = 0; j < 4; ++j) {
        int row = m0 + wr * 64 + m * 16 + lhi * 4 + j;
        out[(size_t)row * 1024 + col] = acc[m][n][j] + bv;
      }
  }
}

extern "C" void kernel_launch(void* const* d_in, const int* in_sizes, int n_in,
                              void* d_out, int out_size, void* d_ws, size_t ws_size,
                              hipStream_t stream) {
  (void)in_sizes; (void)n_in; (void)out_size; (void)ws_size;
  const float* x      = (const float*)d_in[0];
  const int*   dirp   = (const int*)d_in[1];
  const float* qkv_w  = (const float*)d_in[2];
  const float* qkv_b  = (const float*)d_in[3];
  const float* proj_w = (const float*)d_in[4];
  const float* proj_b = (const float*)d_in[5];
  float* out = (float*)d_out;

  char* ws = (char*)d_ws;
  bf16_t* xb   = (bf16_t*)(ws);                       // 16,777,216 B (reused as a2 after GEMM1)
  bf16_t* wq_t = (bf16_t*)(ws + 16777216);            //  6,291,456 B
  bf16_t* wp_t = (bf16_t*)(ws + 23068672);            //  2,097,152 B
  bf16_t* qb   = (bf16_t*)(ws + 25165824);            // 16,777,216 B
  bf16_t* kb   = (bf16_t*)(ws + 41943040);            // 16,777,216 B
  bf16_t* vtb  = (bf16_t*)(ws + 58720256);            // 16,777,216 B  (end: 75,497,472)
  bf16_t* a2   = xb;

  k_cast<<<8192, 256, 0, stream>>>(x, xb, 2097152);
  k_transpose_cast<<<dim3(96, 32), dim3(32, 8), 0, stream>>>(qkv_w, wq_t, 1024, 3072);
  k_transpose_cast<<<dim3(32, 32), dim3(32, 8), 0, stream>>>(proj_w, wp_t, 1024, 1024);
  k_gemm_qkv<<<dim3(64, 24), 256, 0, stream>>>(xb, wq_t, qkv_b, qb, kb, vtb);
  k_attn2<<<dim3(64, 16), 256, 0, stream>>>(qb, kb, vtb, dirp, a2);
  k_gemm_proj<<<dim3(64, 8), 256, 0, stream>>>(a2, wp_t, proj_b, out);
}

// Round 3
// 198.630 us; speedup vs baseline: 1.9258x; 1.7922x over previous
//
#include <hip/hip_runtime.h>
#include <math.h>

typedef __bf16 bf16_t;
typedef bf16_t bf16x8 __attribute__((ext_vector_type(8)));
typedef bf16_t bf16x4 __attribute__((ext_vector_type(4)));
typedef float  f32x4  __attribute__((ext_vector_type(4)));
typedef float  floatv4 __attribute__((ext_vector_type(4)));

#define AS1 __attribute__((address_space(1)))
#define AS3 __attribute__((address_space(3)))

static __device__ __forceinline__ void gld_lds16(const void* g, void* l) {
  __builtin_amdgcn_global_load_lds((const AS1 unsigned int*)g,
                                   (AS3 unsigned int*)l, 16, 0, 0);
}
static __device__ __forceinline__ void block_sync() {
  asm volatile("" ::: "memory");
  __builtin_amdgcn_s_barrier();
  asm volatile("" ::: "memory");
}

// ---------------- cast f32 -> bf16, 4 elems/thread ----------------
__global__ __launch_bounds__(256) void k_cast(const float* __restrict__ in,
                                              bf16_t* __restrict__ out, int n4) {
  int i = blockIdx.x * 256 + threadIdx.x;
  if (i >= n4) return;
  floatv4 v = ((const floatv4*)in)[i];
  bf16x4 o;
  o.x = (bf16_t)v.x; o.y = (bf16_t)v.y; o.z = (bf16_t)v.z; o.w = (bf16_t)v.w;
  ((bf16x4*)out)[i] = o;
}

// ---------------- transpose + cast: in f32 [R][Cc] -> out bf16 [Cc][R] ----------------
__global__ __launch_bounds__(256) void k_transpose_cast(const float* __restrict__ in,
                                                        bf16_t* __restrict__ out,
                                                        int R, int Cc) {
  __shared__ float tile[32][33];
  int c0 = blockIdx.x * 32, r0 = blockIdx.y * 32;
  int tx = threadIdx.x, ty = threadIdx.y;  // 32 x 8
#pragma unroll
  for (int i = 0; i < 32; i += 8)
    tile[ty + i][tx] = in[(size_t)(r0 + ty + i) * Cc + c0 + tx];
  __syncthreads();
#pragma unroll
  for (int i = 0; i < 32; i += 8)
    out[(size_t)(c0 + ty + i) * R + r0 + tx] = (bf16_t)tile[tx][ty + i];
}

// ---------------- GEMM1: qkv = X @ Wt^T, scatter to q(scaled)/k/v(trans) bf16 ----------------
__global__ __launch_bounds__(256) void k_gemm_qkv(
    const bf16_t* __restrict__ A, const bf16_t* __restrict__ Bt,
    const float* __restrict__ bias,
    bf16_t* __restrict__ qo, bf16_t* __restrict__ ko, bf16_t* __restrict__ vto) {
  const int K = 1024;
  __shared__ bf16_t As[128 * 32];
  __shared__ bf16_t Bs[128 * 32];
  const int m0 = blockIdx.x * 128, n0 = blockIdx.y * 128;
  const int t = threadIdx.x, lane = t & 63, w = t >> 6;
  const int wr = w >> 1, wc = w & 1;
  const int ln15 = lane & 15, lhi = lane >> 4;

  f32x4 acc[4][4];
#pragma unroll
  for (int m = 0; m < 4; ++m)
#pragma unroll
    for (int n = 0; n < 4; ++n) acc[m][n] = (f32x4){0.f, 0.f, 0.f, 0.f};

  const int sr = t >> 2, sc = (t & 3) * 8;
  const bf16_t* Ab = A + (size_t)(m0 + sr) * K + sc;
  const bf16_t* Bb = Bt + (size_t)(n0 + sr) * K + sc;
  char* AsDst = (char*)As + t * 16;
  char* BsDst = (char*)Bs + t * 16;

  for (int k0 = 0; k0 < K; k0 += 32) {
    gld_lds16(Ab + k0, AsDst);
    gld_lds16(Ab + 64 * K + k0, AsDst + 4096);
    gld_lds16(Bb + k0, BsDst);
    gld_lds16(Bb + 64 * K + k0, BsDst + 4096);
    __syncthreads();
    bf16x8 af[4], bfr[4];
#pragma unroll
    for (int m = 0; m < 4; ++m)
      af[m] = *(const bf16x8*)&As[(wr * 64 + m * 16 + ln15) * 32 + lhi * 8];
#pragma unroll
    for (int n = 0; n < 4; ++n)
      bfr[n] = *(const bf16x8*)&Bs[(wc * 64 + n * 16 + ln15) * 32 + lhi * 8];
#pragma unroll
    for (int m = 0; m < 4; ++m)
#pragma unroll
      for (int n = 0; n < 4; ++n)
        acc[m][n] = __builtin_amdgcn_mfma_f32_16x16x32_bf16(af[m], bfr[n], acc[m][n], 0, 0, 0);
    __syncthreads();
  }
#pragma unroll
  for (int n = 0; n < 4; ++n) {
    int col = n0 + wc * 64 + n * 16 + ln15;
    float bv = bias[col];
    int which = col >> 10;
    int cc = col & 1023;
    int h = cc >> 6, d = cc & 63;
#pragma unroll
    for (int m = 0; m < 4; ++m)
#pragma unroll
      for (int j = 0; j < 4; ++j) {
        int row = m0 + wr * 64 + m * 16 + lhi * 4 + j;
        int b = row >> 11, tt = row & 2047;
        float o = acc[m][n][j] + bv;
        if (which == 0) o *= 0.18033688011112042f;  // 0.125 * log2(e), pre-scale Q
        bf16_t ob = (bf16_t)o;
        size_t bh = (size_t)(b * 16 + h);
        if (which == 0)      qo[(bh * 2048 + tt) * 64 + d] = ob;
        else if (which == 1) ko[(bh * 2048 + tt) * 64 + d] = ob;
        else                 vto[(bh * 64 + d) * 2048 + tt] = ob;
      }
  }
}

// ---------------- flash attention v3: LDS-staged K/V (fragment-order), KVBLK=64 ----------------
// LDS layout per buf (16KB): K 8KB at +0, V 8KB at +8192 (bytes).
// K chunk qk (0..7): kh=qk>>2, c=(qk>>1)&1, h2=qk&1; lane supplies
//   K[kc0 + kh*32 + c*4 + ((lane&15)>>2)*8 + (lane&3)][d: (lane>>4)*8 + h2*32 ..+8]
// stored at byte (qk*64+lane)*16 -> ds_read_b128 lane-linear (conflict-free).
// V chunk gv (0..7): d-group gv&3, k-half gv>>2; lane supplies
//   V^T[(gv&3)*16 + (lane&15)][kc0 + (gv>>2)*32 + (lane>>4)*8 ..+8]
__global__ __launch_bounds__(256) void k_attn3(
    const bf16_t* __restrict__ q, const bf16_t* __restrict__ k,
    const bf16_t* __restrict__ vt, const int* __restrict__ dirp,
    bf16_t* __restrict__ a2) {
  const int T = 2048;
  __shared__ __align__(16) bf16_t smem[16384];  // 32 KB: 2 bufs x 16KB
  const int bh = blockIdx.x, b = bh >> 4, h = bh & 15;
  const int jb = blockIdx.y;  // pair {jb, 31-jb}: uniform 33 k64-blocks/block
  const int t = threadIdx.x, lane = t & 63, w = t >> 6;
  const int ln15 = lane & 15, lhi = lane >> 4;
  const bool anti = (*dirp == 1);

  const bf16_t* kbase = k + (size_t)bh * T * 64;
  const bf16_t* vbase = vt + (size_t)bh * 64 * T;

  auto stage = [&](int kc0, int buf) {
    char* Kd = (char*)smem + buf * 16384;
    char* Vd = Kd + 8192;
#pragma unroll
    for (int s = 0; s < 2; ++s) {
      const int qk = s * 4 + (t >> 6);
      const int krow = kc0 + (qk >> 2) * 32 + ((qk >> 1) & 1) * 4 +
                       ((lane & 15) >> 2) * 8 + (lane & 3);
      const int kcolb = (lane >> 4) * 16 + (qk & 1) * 64;
      gld_lds16((const char*)kbase + (size_t)krow * 128 + kcolb,
                Kd + s * 4096 + t * 16);
      const int gv = qk;
      const int vd = (gv & 3) * 16 + (lane & 15);
      gld_lds16((const char*)vbase + (size_t)vd * 4096 + (size_t)kc0 * 2 +
                    (gv >> 2) * 64 + (lane >> 4) * 16,
                Vd + s * 4096 + t * 16);
    }
  };

#pragma unroll 1
  for (int sel = 0; sel < 2; ++sel) {
    const int qt = sel ? (31 - jb) : jb;
    const int q0 = qt * 64 + w * 16;
    const int qrow = q0 + ln15;

    const bf16_t* qp = q + ((size_t)bh * T + qrow) * 64 + lhi * 8;
    bf16x8 qf0 = *(const bf16x8*)qp;
    bf16x8 qf1 = *(const bf16x8*)(qp + 32);

    f32x4 acc[4];
#pragma unroll
    for (int g = 0; g < 4; ++g) acc[g] = (f32x4){0.f, 0.f, 0.f, 0.f};
    float mrun = -3.0e38f, lrun = 0.f;

    const int kt0 = anti ? qt : 0;
    const int nb = anti ? (32 - qt) : (qt + 1);

    stage(kt0 * 64, 0);
#pragma unroll 1
    for (int i = 0; i < nb; ++i) {
      const int kt = kt0 + i;
      const int buf = i & 1;
      if (i + 1 < nb) {
        stage((kt + 1) * 64, buf ^ 1);
        asm volatile("s_waitcnt vmcnt(4)" ::: "memory");
      } else {
        asm volatile("s_waitcnt vmcnt(0)" ::: "memory");
      }
      block_sync();
      const bf16_t* Kb = smem + buf * 8192;  // bf16 units (16384 B)
      const bf16_t* Vb = Kb + 4096;

      float sc[16];
#pragma unroll
      for (int kh = 0; kh < 2; ++kh) {
        bf16x8 k0 = *(const bf16x8*)(Kb + (kh * 4 + 0) * 512 + lane * 8);
        bf16x8 k1 = *(const bf16x8*)(Kb + (kh * 4 + 1) * 512 + lane * 8);
        bf16x8 k2 = *(const bf16x8*)(Kb + (kh * 4 + 2) * 512 + lane * 8);
        bf16x8 k3 = *(const bf16x8*)(Kb + (kh * 4 + 3) * 512 + lane * 8);
        const f32x4 zz = (f32x4){0.f, 0.f, 0.f, 0.f};
        f32x4 slo = __builtin_amdgcn_mfma_f32_16x16x32_bf16(k0, qf0, zz, 0, 0, 0);
        slo = __builtin_amdgcn_mfma_f32_16x16x32_bf16(k1, qf1, slo, 0, 0, 0);
        f32x4 shi = __builtin_amdgcn_mfma_f32_16x16x32_bf16(k2, qf0, zz, 0, 0, 0);
        shi = __builtin_amdgcn_mfma_f32_16x16x32_bf16(k3, qf1, shi, 0, 0, 0);
#pragma unroll
        for (int j = 0; j < 4; ++j) {
          sc[kh * 8 + j] = slo[j];
          sc[kh * 8 + 4 + j] = shi[j];
        }
      }
      if (kt == qt) {  // diagonal block: apply mask
#pragma unroll
        for (int e = 0; e < 16; ++e) {
          const int col = kt * 64 + (e >> 3) * 32 + lhi * 8 + (e & 7);
          const bool ok = anti ? (col >= qrow) : (col <= qrow);
          sc[e] = ok ? sc[e] : -3.0e38f;
        }
      }
      float lmax = sc[0];
#pragma unroll
      for (int e = 1; e < 16; ++e) lmax = fmaxf(lmax, sc[e]);
      if (!__all(lmax <= mrun + 8.f)) {
        float vm = lmax;
        vm = fmaxf(vm, __shfl_xor(vm, 16));
        vm = fmaxf(vm, __shfl_xor(vm, 32));
        const float mn = fmaxf(mrun, vm);
        const float al = __builtin_amdgcn_exp2f(mrun - mn);
        lrun *= al;
#pragma unroll
        for (int g = 0; g < 4; ++g) acc[g] *= al;
        mrun = mn;
      }
      bf16x8 pb0, pb1;
      float rs = 0.f;
#pragma unroll
      for (int e = 0; e < 8; ++e) {
        float p = __builtin_amdgcn_exp2f(sc[e] - mrun);
        rs += p; pb0[e] = (bf16_t)p;
      }
#pragma unroll
      for (int e = 0; e < 8; ++e) {
        float p = __builtin_amdgcn_exp2f(sc[8 + e] - mrun);
        rs += p; pb1[e] = (bf16_t)p;
      }
      lrun += rs;
#pragma unroll
      for (int dg = 0; dg < 4; ++dg) {
        bf16x8 v0 = *(const bf16x8*)(Vb + dg * 512 + lane * 8);
        acc[dg] = __builtin_amdgcn_mfma_f32_16x16x32_bf16(v0, pb0, acc[dg], 0, 0, 0);
      }
#pragma unroll
      for (int dg = 0; dg < 4; ++dg) {
        bf16x8 v1 = *(const bf16x8*)(Vb + (4 + dg) * 512 + lane * 8);
        acc[dg] = __builtin_amdgcn_mfma_f32_16x16x32_bf16(v1, pb1, acc[dg], 0, 0, 0);
      }
      block_sync();
    }

    lrun += __shfl_xor(lrun, 16);
    lrun += __shfl_xor(lrun, 32);
    const float inv = __builtin_amdgcn_rcpf(lrun);
    bf16_t* op = a2 + ((size_t)b * T + qrow) * 1024 + h * 64 + lhi * 4;
#pragma unroll
    for (int g = 0; g < 4; ++g) {
      bf16x4 o4;
#pragma unroll
      for (int jx = 0; jx < 4; ++jx) o4[jx] = (bf16_t)(acc[g][jx] * inv);
      *(bf16x4*)(op + g * 16) = o4;
    }
  }
}

// ---------------- GEMM2: out = A2 @ Wp^T + bias, fp32 out ----------------
__global__ __launch_bounds__(256) void k_gemm_proj(
    const bf16_t* __restrict__ A, const bf16_t* __restrict__ Bt,
    const float* __restrict__ bias, float* __restrict__ out) {
  const int K = 1024;
  __shared__ bf16_t As[128 * 32];
  __shared__ bf16_t Bs[128 * 32];
  const int m0 = blockIdx.x * 128, n0 = blockIdx.y * 128;
  const int t = threadIdx.x, lane = t & 63, w = t >> 6;
  const int wr = w >> 1, wc = w & 1;
  const int ln15 = lane & 15, lhi = lane >> 4;

  f32x4 acc[4][4];
#pragma unroll
  for (int m = 0; m < 4; ++m)
#pragma unroll
    for (int n = 0; n < 4; ++n) acc[m][n] = (f32x4){0.f, 0.f, 0.f, 0.f};

  const int sr = t >> 2, sc = (t & 3) * 8;
  const bf16_t* Ab = A + (size_t)(m0 + sr) * K + sc;
  const bf16_t* Bb = Bt + (size_t)(n0 + sr) * K + sc;
  char* AsDst = (char*)As + t * 16;
  char* BsDst = (char*)Bs + t * 16;

  for (int k0 = 0; k0 < K; k0 += 32) {
    gld_lds16(Ab + k0, AsDst);
    gld_lds16(Ab + 64 * K + k0, AsDst + 4096);
    gld_lds16(Bb + k0, BsDst);
    gld_lds16(Bb + 64 * K + k0, BsDst + 4096);
    __syncthreads();
    bf16x8 af[4], bfr[4];
#pragma unroll
    for (int m = 0; m < 4; ++m)
      af[m] = *(const bf16x8*)&As[(wr * 64 + m * 16 + ln15) * 32 + lhi * 8];
#pragma unroll
    for (int n = 0; n < 4; ++n)
      bfr[n] = *(const bf16x8*)&Bs[(wc * 64 + n * 16 + ln15) * 32 + lhi * 8];
#pragma unroll
    for (int m = 0; m < 4; ++m)
#pragma unroll
      for (int n = 0; n < 4; ++n)
        acc[m][n] = __builtin_amdgcn_mfma_f32_16x16x32_bf16(af[m], bfr[n], acc[m][n], 0, 0, 0);
    __syncthreads();
  }
#pragma unroll
  for (int n = 0; n < 4; ++n) {
    int col = n0 + wc * 64 + n * 16 + ln15;
    float bv = bias[col];
#pragma unroll
    for (int m = 0; m < 4; ++m)
#pragma unroll
      for (int j = 0; j < 4; ++j) {
        int row = m0 + wr * 64 + m * 16 + lhi * 4 + j;
        out[(size_t)row * 1024 + col] = acc[m][n][j] + bv;
      }
  }
}

extern "C" void kernel_launch(void* const* d_in, const int* in_sizes, int n_in,
                              void* d_out, int out_size, void* d_ws, size_t ws_size,
                              hipStream_t stream) {
  (void)in_sizes; (void)n_in; (void)out_size; (void)ws_size;
  const float* x      = (const float*)d_in[0];
  const int*   dirp   = (const int*)d_in[1];
  const float* qkv_w  = (const float*)d_in[2];
  const float* qkv_b  = (const float*)d_in[3];
  const float* proj_w = (const float*)d_in[4];
  const float* proj_b = (const float*)d_in[5];
  float* out = (float*)d_out;

  char* ws = (char*)d_ws;
  bf16_t* xb   = (bf16_t*)(ws);                       // 16,777,216 B (reused as a2)
  bf16_t* wq_t = (bf16_t*)(ws + 16777216);            //  6,291,456 B
  bf16_t* wp_t = (bf16_t*)(ws + 23068672);            //  2,097,152 B
  bf16_t* qb   = (bf16_t*)(ws + 25165824);            // 16,777,216 B
  bf16_t* kb   = (bf16_t*)(ws + 41943040);            // 16,777,216 B
  bf16_t* vtb  = (bf16_t*)(ws + 58720256);            // 16,777,216 B (end: 75,497,472)
  bf16_t* a2   = xb;

  k_cast<<<8192, 256, 0, stream>>>(x, xb, 2097152);
  k_transpose_cast<<<dim3(96, 32), dim3(32, 8), 0, stream>>>(qkv_w, wq_t, 1024, 3072);
  k_transpose_cast<<<dim3(32, 32), dim3(32, 8), 0, stream>>>(proj_w, wp_t, 1024, 1024);
  k_gemm_qkv<<<dim3(64, 24), 256, 0, stream>>>(xb, wq_t, qkv_b, qb, kb, vtb);
  k_attn3<<<dim3(64, 16), 256, 0, stream>>>(qb, kb, vtb, dirp, a2);
  k_gemm_proj<<<dim3(64, 8), 256, 0, stream>>>(a2, wp_t, proj_b, out);
}